// Round 2
// baseline (218.644 us; speedup 1.0000x reference)
//
#include <hip/hip_runtime.h>

#define T_TEST 8192
#define BB 8
#define FF 100
#define HH 512

typedef __bf16 bf16x8 __attribute__((ext_vector_type(8)));
typedef float f32x4 __attribute__((ext_vector_type(4)));
typedef unsigned short u16;
typedef unsigned int u32;

__device__ __forceinline__ u16 f2bf(float f) {
    u32 u = __float_as_uint(f);
    u += 0x7fffu + ((u >> 16) & 1);   // RNE
    return (u16)(u >> 16);
}

__device__ __forceinline__ float nan2num(float v) {
    u32 u = __float_as_uint(v);
    if ((u & 0x7f800000u) == 0x7f800000u) {
        v = (u & 0x007fffffu) ? 0.f : ((u >> 31) ? -3.3895314e38f : 3.3895314e38f);
    }
    return v;
}

// ---- weight prep: fragment-major bf16 layouts -------------------------
// w1f[b][n16(32)][kk(4)][lane(64)][j(8)] : value = w1[b][k=kk*32+q*8+j][n=n16*16+c]
__global__ void prep_w1f(const float* __restrict__ w1, u16* __restrict__ w1f) {
    int tid = blockIdx.x * 256 + threadIdx.x;       // 65536 threads
    int lane = tid & 63;
    int kk = (tid >> 6) & 3;
    int n16 = (tid >> 8) & 31;
    int b = tid >> 13;
    int cc = lane & 15, qq = lane >> 4;
    int n = n16 * 16 + cc;
    u32 p[4];
#pragma unroll
    for (int jp = 0; jp < 4; ++jp) {
        int k0 = kk * 32 + qq * 8 + jp * 2;
        float v0 = (k0 < FF)     ? w1[(b * FF + k0) * HH + n]     : 0.f;
        float v1 = (k0 + 1 < FF) ? w1[(b * FF + k0 + 1) * HH + n] : 0.f;
        p[jp] = (u32)f2bf(v0) | ((u32)f2bf(v1) << 16);
    }
    uint4 o = {p[0], p[1], p[2], p[3]};
    *(uint4*)(w1f + (size_t)tid * 8) = o;
}

// w2f[b][n16(32)][kk(16)][lane(64)][j(8)] : value = w2[b][k=kk*32+q*8+j][n=n16*16+c]
__global__ void prep_w2f(const float* __restrict__ w2, u16* __restrict__ w2f) {
    int tid = blockIdx.x * 256 + threadIdx.x;       // 262144 threads
    int lane = tid & 63;
    int kk = (tid >> 6) & 15;
    int n16 = (tid >> 10) & 31;
    int b = tid >> 15;
    int cc = lane & 15, qq = lane >> 4;
    int n = n16 * 16 + cc;
    u32 p[4];
#pragma unroll
    for (int jp = 0; jp < 4; ++jp) {
        int k0 = kk * 32 + qq * 8 + jp * 2;
        float v0 = w2[(b * HH + k0) * HH + n];
        float v1 = w2[(b * HH + k0 + 1) * HH + n];
        p[jp] = (u32)f2bf(v0) | ((u32)f2bf(v1) << 16);
    }
    uint4 o = {p[0], p[1], p[2], p[3]};
    *(uint4*)(w2f + (size_t)tid * 8) = o;
}

// ---- fused 3-layer MLP ------------------------------------------------
// One block = 128 rows of one batch. x->LDS, h1 chunk in LDS (k-chunked),
// layer-2 acc in registers across chunks, layer-3 fold in-register.
__global__ __launch_bounds__(512, 2) void fused_mlp(
    const float* __restrict__ x, const u16* __restrict__ w1f,
    const float* __restrict__ b1, const u16* __restrict__ w2f,
    const float* __restrict__ b2, const float* __restrict__ w3,
    const float* __restrict__ b3, float* __restrict__ out) {
    __shared__ __align__(16) u16 x_lds[128 * 128];   // swizzled: phys = r*128 + ((g^ (r&7))<<3)+(k&7)
    __shared__ __align__(16) u16 h1_lds[128 * 128];  // same swizzle, k-chunk of h1

    const int tid = threadIdx.x;
    const int b = blockIdx.x;          // batch -> XCD affinity
    const int m0 = blockIdx.y * 128;
    const int lane = tid & 63;
    const int w = tid >> 6;            // wave 0..7, owns rows w*16..w*16+15
    const int c = lane & 15, q = lane >> 4;

    // ---- stage x into LDS (bf16, swizzled, zero-padded k in [100,128)) ----
    {
        int row = tid >> 2, j4 = tid & 3;
        int gz = 12 + j4;              // zero granules 12..15 (k 96..127)
        int pz = row * 128 + ((gz ^ (row & 7)) << 3);
        int4 z = {0, 0, 0, 0};
        *(int4*)(&x_lds[pz]) = z;
        const float* xr = x + ((size_t)(m0 + row) * BB + b) * FF;
#pragma unroll
        for (int jj = j4; jj < 25; jj += 4) {     // 25 float4 = 100 floats
            float4 v = *(const float4*)(xr + jj * 4);
            ushort4 h;
            h.x = f2bf(nan2num(v.x));
            h.y = f2bf(nan2num(v.y));
            h.z = f2bf(nan2num(v.z));
            h.w = f2bf(nan2num(v.w));
            int k = jj * 4;
            int ph = row * 128 + (((k >> 3) ^ (row & 7)) << 3) + (k & 7);
            *(ushort4*)(&x_lds[ph]) = h;
        }
    }
    __syncthreads();

    const u16* w1fb = w1f + (size_t)b * (32 * 4 * 512);
    const u16* w2fb = w2f + (size_t)b * (32 * 16 * 512);
    const int rloc = w * 16 + c;       // this lane's A-operand row (local)
    const int r7 = rloc & 7;

    f32x4 accb[4][8];                  // layer-2 accumulators: [ntb][ni]
#pragma unroll
    for (int i = 0; i < 4; ++i)
#pragma unroll
        for (int j = 0; j < 8; ++j)
            accb[i][j] = (f32x4){0.f, 0.f, 0.f, 0.f};

    for (int nta = 0; nta < 4; ++nta) {   // h1 column chunk == layer-2 k chunk
        // ---- stage A: h1[:, nta*128 .. +128) ----
        f32x4 acca[8] = {};
#pragma unroll
        for (int kk = 0; kk < 4; ++kk) {
            int g = kk * 4 + q;
            bf16x8 af = *(const bf16x8*)(&x_lds[rloc * 128 + ((g ^ r7) << 3)]);
#pragma unroll
            for (int ni = 0; ni < 8; ++ni) {
                int n16 = nta * 8 + ni;
                bf16x8 bf = *(const bf16x8*)(w1fb + ((n16 * 4 + kk) << 9) + lane * 8);
                acca[ni] = __builtin_amdgcn_mfma_f32_16x16x32_bf16(af, bf, acca[ni], 0, 0, 0);
            }
        }
        __syncthreads();   // all waves done reading h1 chunk of prev iter
        // epilogue: relu(acca + b1) -> h1_lds (paired b32 writes, swizzled)
        u32* h32 = (u32*)h1_lds;
#pragma unroll
        for (int ni = 0; ni < 8; ++ni) {
            int n = nta * 128 + ni * 16 + c;
            float b1v = b1[b * HH + n];
            u32 own01 = (u32)f2bf(fmaxf(acca[ni][0] + b1v, 0.f)) |
                        ((u32)f2bf(fmaxf(acca[ni][1] + b1v, 0.f)) << 16);
            u32 own23 = (u32)f2bf(fmaxf(acca[ni][2] + b1v, 0.f)) |
                        ((u32)f2bf(fmaxf(acca[ni][3] + b1v, 0.f)) << 16);
            u32 oth01 = __shfl_xor(own01, 1, 64);
            u32 oth23 = __shfl_xor(own23, 1, 64);
            int row0 = w * 16 + q * 4;
            int ncol = (ni * 16 + c) & ~1;
            int gw = ncol >> 3;
            if (!(c & 1)) {
                u32 d0 = (own01 & 0xffffu) | (oth01 << 16);
                u32 d1 = (own01 >> 16) | (oth01 & 0xffff0000u);
                int p0 = row0 * 128 + ((gw ^ (row0 & 7)) << 3) + (ncol & 7);
                int p1 = (row0 + 1) * 128 + ((gw ^ ((row0 + 1) & 7)) << 3) + (ncol & 7);
                h32[p0 >> 1] = d0;
                h32[p1 >> 1] = d1;
            } else {
                u32 d2 = (oth23 & 0xffffu) | (own23 << 16);
                u32 d3 = (oth23 >> 16) | (own23 & 0xffff0000u);
                int p2 = (row0 + 2) * 128 + ((gw ^ ((row0 + 2) & 7)) << 3) + (ncol & 7);
                int p3 = (row0 + 3) * 128 + ((gw ^ ((row0 + 3) & 7)) << 3) + (ncol & 7);
                h32[p2 >> 1] = d2;
                h32[p3 >> 1] = d3;
            }
        }
        __syncthreads();   // h1 chunk visible to all waves
        // ---- stage B partial: accumulate this k-chunk into accb ----
#pragma unroll
        for (int ntb = 0; ntb < 4; ++ntb)
#pragma unroll
            for (int kk2 = 0; kk2 < 4; ++kk2) {
                int g2 = kk2 * 4 + q;
                bf16x8 af2 = *(const bf16x8*)(&h1_lds[rloc * 128 + ((g2 ^ r7) << 3)]);
#pragma unroll
                for (int ni = 0; ni < 8; ++ni) {
                    int n16 = ntb * 8 + ni;
                    int kkg = nta * 4 + kk2;
                    bf16x8 bf = *(const bf16x8*)(w2fb + ((n16 * 16 + kkg) << 9) + lane * 8);
                    accb[ntb][ni] = __builtin_amdgcn_mfma_f32_16x16x32_bf16(af2, bf, accb[ntb][ni], 0, 0, 0);
                }
            }
    }

    // ---- layer-3 fold + reduce + store (each row owned by one wave) ----
    float psum[4] = {0.f, 0.f, 0.f, 0.f};
#pragma unroll
    for (int ntb = 0; ntb < 4; ++ntb)
#pragma unroll
        for (int ni = 0; ni < 8; ++ni) {
            int n = ntb * 128 + ni * 16 + c;
            float b2v = b2[b * HH + n];
            float w3v = w3[b * HH + n];
#pragma unroll
            for (int r = 0; r < 4; ++r)
                psum[r] += fmaxf(accb[ntb][ni][r] + b2v, 0.f) * w3v;
        }
    float b3v = b3[b];
#pragma unroll
    for (int r = 0; r < 4; ++r) {
        float v = psum[r];
        v += __shfl_xor(v, 1, 64);
        v += __shfl_xor(v, 2, 64);
        v += __shfl_xor(v, 4, 64);
        v += __shfl_xor(v, 8, 64);
        if (c == 0) {
            int rowg = m0 + w * 16 + q * 4 + r;
            out[rowg * BB + b] = v + b3v;
        }
    }
}

extern "C" void kernel_launch(void* const* d_in, const int* in_sizes, int n_in,
                              void* d_out, int out_size, void* d_ws, size_t ws_size,
                              hipStream_t stream) {
    const float* x  = (const float*)d_in[0];
    const float* w1 = (const float*)d_in[1];
    const float* b1 = (const float*)d_in[2];
    const float* w2 = (const float*)d_in[3];
    const float* b2 = (const float*)d_in[4];
    const float* w3 = (const float*)d_in[5];
    const float* b3 = (const float*)d_in[6];
    float* out = (float*)d_out;

    u16* w1f = (u16*)d_ws;                              // 8*32*4*512  bf16 = 1 MB
    u16* w2f = w1f + (size_t)BB * 32 * 4 * 512;         // 8*32*16*512 bf16 = 8 MB

    prep_w1f<<<(BB * 32 * 4 * 64) / 256, 256, 0, stream>>>(w1, w1f);
    prep_w2f<<<(BB * 32 * 16 * 64) / 256, 256, 0, stream>>>(w2, w2f);

    // grid.x = batch (XCD round-robin affinity), grid.y = 128-row tile
    fused_mlp<<<dim3(BB, T_TEST / 128), 512, 0, stream>>>(
        x, w1f, b1, w2f, b2, w3, b3, out);
}

// Round 3
// 185.978 us; speedup vs baseline: 1.1756x; 1.1756x over previous
//
#include <hip/hip_runtime.h>

#define T_TEST 8192
#define BB 8
#define FF 100
#define HH 512

typedef __bf16 bf16x8 __attribute__((ext_vector_type(8)));
typedef float f32x4 __attribute__((ext_vector_type(4)));
typedef unsigned short u16;
typedef unsigned int u32;

__device__ __forceinline__ u16 f2bf(float f) {
    u32 u = __float_as_uint(f);
    u += 0x7fffu + ((u >> 16) & 1);   // RNE
    return (u16)(u >> 16);
}

__device__ __forceinline__ float nan2num(float v) {
    u32 u = __float_as_uint(v);
    if ((u & 0x7f800000u) == 0x7f800000u) {
        v = (u & 0x007fffffu) ? 0.f : ((u >> 31) ? -3.3895314e38f : 3.3895314e38f);
    }
    return v;
}

// ---- weight prep: fragment-major, group-contiguous layouts -------------
// w1f frag index: ((b*4 + kk)*32 + n16)*64 + lane ; frag = 8 bf16
// value[j] = w1[b][k=kk*32+q*8+j][n=n16*16+c]   (c=lane&15, q=lane>>4)
__global__ void prep_w1f(const float* __restrict__ w1, u16* __restrict__ w1f) {
    int tid = blockIdx.x * 256 + threadIdx.x;       // 65536 threads
    int lane = tid & 63;
    int kk = (tid >> 6) & 3;
    int n16 = (tid >> 8) & 31;
    int b = tid >> 13;
    int cc = lane & 15, qq = lane >> 4;
    int n = n16 * 16 + cc;
    u32 p[4];
#pragma unroll
    for (int jp = 0; jp < 4; ++jp) {
        int k0 = kk * 32 + qq * 8 + jp * 2;
        float v0 = (k0 < FF)     ? w1[(b * FF + k0) * HH + n]     : 0.f;
        float v1 = (k0 + 1 < FF) ? w1[(b * FF + k0 + 1) * HH + n] : 0.f;
        p[jp] = (u32)f2bf(v0) | ((u32)f2bf(v1) << 16);
    }
    uint4 o = {p[0], p[1], p[2], p[3]};
    size_t fi = ((size_t)(b * 4 + kk) * 32 + n16) * 64 + lane;
    *(uint4*)(w1f + fi * 8) = o;
}

// w2f frag index: ((b*16 + kk)*32 + n16)*64 + lane
// value[j] = w2[b][k=kk*32+q*8+j][n=n16*16+c]
__global__ void prep_w2f(const float* __restrict__ w2, u16* __restrict__ w2f) {
    int tid = blockIdx.x * 256 + threadIdx.x;       // 262144 threads
    int lane = tid & 63;
    int kk = (tid >> 6) & 15;
    int n16 = (tid >> 10) & 31;
    int b = tid >> 15;
    int cc = lane & 15, qq = lane >> 4;
    int n = n16 * 16 + cc;
    u32 p[4];
#pragma unroll
    for (int jp = 0; jp < 4; ++jp) {
        int k0 = kk * 32 + qq * 8 + jp * 2;
        float v0 = w2[(b * HH + k0) * HH + n];
        float v1 = w2[(b * HH + k0 + 1) * HH + n];
        p[jp] = (u32)f2bf(v0) | ((u32)f2bf(v1) << 16);
    }
    uint4 o = {p[0], p[1], p[2], p[3]};
    size_t fi = ((size_t)(b * 16 + kk) * 32 + n16) * 64 + lane;
    *(uint4*)(w2f + fi * 8) = o;
}

// ---- fused 3-layer MLP: 64 rows/block, 4 waves, rows wave-private, ----
// ---- zero barriers, h1 fully LDS-resident (chunk-major 4 x 16KB)   ----
__global__ __launch_bounds__(256, 2) void fused_mlp(
    const float* __restrict__ x, const u16* __restrict__ w1f,
    const float* __restrict__ b1, const u16* __restrict__ w2f,
    const float* __restrict__ b2, const float* __restrict__ w3,
    const float* __restrict__ b3, float* __restrict__ out) {
    // lds: 4 chunks of [64 rows][128 cols] bf16, 16KB each. Chunk nta holds
    // h1 cols nta*128..+128. x (bf16, k-padded to 128) staged in chunk 3,
    // overwritten by h1 chunk 3 last. Swizzle: phys col-granule = g ^ (row&7).
    __shared__ __align__(16) u16 lds[4 * 8192];

    const int tid = threadIdx.x;
    const int b = blockIdx.x;              // batch -> XCD affinity (linear%8==b)
    const int m0 = blockIdx.y * 64;
    const int lane = tid & 63;
    const int w = tid >> 6;                // wave 0..3 owns rows w*16..+15
    const int c = lane & 15, q = lane >> 4;
    const int rloc = w * 16 + c;
    const int r7 = rloc & 7;

    // ---- stage x rows (wave-private: tid>>2 in [w*16, w*16+16)) ----
    {
        int row = tid >> 2, j4 = tid & 3;
        int gz = 12 + j4;                  // zero granules (k 96..127)
        int pz = 3 * 8192 + row * 128 + ((gz ^ (row & 7)) << 3);
        int4 z = {0, 0, 0, 0};
        *(int4*)(&lds[pz]) = z;
        const float* xr = x + ((size_t)(m0 + row) * BB + b) * FF;
#pragma unroll
        for (int jj = j4; jj < 25; jj += 4) {   // 25 float4 = 100 floats
            float4 v = *(const float4*)(xr + jj * 4);
            ushort4 h;
            h.x = f2bf(nan2num(v.x));
            h.y = f2bf(nan2num(v.y));
            h.z = f2bf(nan2num(v.z));
            h.w = f2bf(nan2num(v.w));
            int k = jj * 4;
            int ph = 3 * 8192 + row * 128 + (((k >> 3) ^ (row & 7)) << 3) + (k & 7);
            *(ushort4*)(&lds[ph]) = h;
        }
    }

    const bf16x8* W1 = (const bf16x8*)w1f + (size_t)b * 8192;   // 4*32*64 frags
    const bf16x8* W2 = (const bf16x8*)w2f + (size_t)b * 32768;  // 16*32*64 frags
    const float* b1g = b1 + b * HH;
    const float* b2g = b2 + b * HH;
    const float* w3g = w3 + b * HH;

    // ---- layer 1: A = x (LDS chunk 3), B = w1f, depth-2 prefetch ----
    auto l1_pass = [&](f32x4* A, int nta) {
        bf16x8 bp[2][8];
#pragma unroll
        for (int ni = 0; ni < 8; ++ni) {
            bp[0][ni] = W1[(0 * 32 + nta * 8 + ni) * 64 + lane];
            bp[1][ni] = W1[(1 * 32 + nta * 8 + ni) * 64 + lane];
        }
#pragma unroll
        for (int kk = 0; kk < 4; ++kk) {
            int g = kk * 4 + q;
            bf16x8 af = *(const bf16x8*)(&lds[3 * 8192 + rloc * 128 + ((g ^ r7) << 3)]);
#pragma unroll
            for (int ni = 0; ni < 8; ++ni)
                A[ni] = __builtin_amdgcn_mfma_f32_16x16x32_bf16(af, bp[kk & 1][ni], A[ni], 0, 0, 0);
            if (kk < 2) {
#pragma unroll
                for (int ni = 0; ni < 8; ++ni)
                    bp[kk & 1][ni] = W1[((kk + 2) * 32 + nta * 8 + ni) * 64 + lane];
            }
        }
    };

    // epilogue: relu(A + b1) -> lds chunk nta (paired dword writes, swizzled)
    auto write_chunk = [&](const f32x4* A, int nta) {
        u32* h32 = (u32*)lds;
        const int cb = nta * 8192;
#pragma unroll
        for (int ni = 0; ni < 8; ++ni) {
            int n = nta * 128 + ni * 16 + c;
            float b1v = b1g[n];
            u32 own01 = (u32)f2bf(fmaxf(A[ni][0] + b1v, 0.f)) |
                        ((u32)f2bf(fmaxf(A[ni][1] + b1v, 0.f)) << 16);
            u32 own23 = (u32)f2bf(fmaxf(A[ni][2] + b1v, 0.f)) |
                        ((u32)f2bf(fmaxf(A[ni][3] + b1v, 0.f)) << 16);
            u32 oth01 = __shfl_xor(own01, 1, 64);
            u32 oth23 = __shfl_xor(own23, 1, 64);
            int row0 = w * 16 + q * 4;
            int ncol = (ni * 16 + c) & ~1;
            int gw = ncol >> 3;
            if (!(c & 1)) {
                u32 d0 = (own01 & 0xffffu) | (oth01 << 16);
                u32 d1 = (own01 >> 16) | (oth01 & 0xffff0000u);
                int p0 = cb + row0 * 128 + ((gw ^ (row0 & 7)) << 3) + (ncol & 7);
                int p1 = cb + (row0 + 1) * 128 + ((gw ^ ((row0 + 1) & 7)) << 3) + (ncol & 7);
                h32[p0 >> 1] = d0;
                h32[p1 >> 1] = d1;
            } else {
                u32 d2 = (oth23 & 0xffffu) | (own23 << 16);
                u32 d3 = (oth23 >> 16) | (own23 & 0xffff0000u);
                int p2 = cb + (row0 + 2) * 128 + ((gw ^ ((row0 + 2) & 7)) << 3) + (ncol & 7);
                int p3 = cb + (row0 + 3) * 128 + ((gw ^ ((row0 + 3) & 7)) << 3) + (ncol & 7);
                h32[p2 >> 1] = d2;
                h32[p3 >> 1] = d3;
            }
        }
    };

    // chunk 3 first (x still needed), write it last (over x region)
    f32x4 accH[8] = {};
    l1_pass(accH, 3);
#pragma unroll
    for (int nta = 0; nta < 3; ++nta) {
        f32x4 acca[8] = {};
        l1_pass(acca, nta);
        write_chunk(acca, nta);
    }
    write_chunk(accH, 3);

    // ---- layer 2 + 3: n in 128-col chunks, full k=512 from LDS ----
    float psum[4] = {0.f, 0.f, 0.f, 0.f};
#pragma unroll
    for (int ntb = 0; ntb < 4; ++ntb) {
        f32x4 accb[8] = {};
        bf16x8 bp[2][8];
#pragma unroll
        for (int ni = 0; ni < 8; ++ni) {
            bp[0][ni] = W2[(0 * 32 + ntb * 8 + ni) * 64 + lane];
            bp[1][ni] = W2[(1 * 32 + ntb * 8 + ni) * 64 + lane];
        }
#pragma unroll
        for (int kk = 0; kk < 16; ++kk) {
            int nchunk = kk >> 2;
            int g2 = ((kk & 3) << 2) + q;
            bf16x8 af = *(const bf16x8*)(&lds[nchunk * 8192 + rloc * 128 + ((g2 ^ r7) << 3)]);
#pragma unroll
            for (int ni = 0; ni < 8; ++ni)
                accb[ni] = __builtin_amdgcn_mfma_f32_16x16x32_bf16(af, bp[kk & 1][ni], accb[ni], 0, 0, 0);
            if (kk < 14) {
#pragma unroll
                for (int ni = 0; ni < 8; ++ni)
                    bp[kk & 1][ni] = W2[((kk + 2) * 32 + ntb * 8 + ni) * 64 + lane];
            }
        }
#pragma unroll
        for (int ni = 0; ni < 8; ++ni) {
            int n = ntb * 128 + ni * 16 + c;
            float b2v = b2g[n];
            float w3v = w3g[n];
#pragma unroll
            for (int r = 0; r < 4; ++r)
                psum[r] += fmaxf(accb[ni][r] + b2v, 0.f) * w3v;
        }
    }

    // ---- reduce across the 16-lane column group, store (rows wave-private) ----
    float b3v = b3[b];
#pragma unroll
    for (int r = 0; r < 4; ++r) {
        float v = psum[r];
        v += __shfl_xor(v, 1, 64);
        v += __shfl_xor(v, 2, 64);
        v += __shfl_xor(v, 4, 64);
        v += __shfl_xor(v, 8, 64);
        if (c == 0) {
            int rowg = m0 + w * 16 + q * 4 + r;
            out[rowg * BB + b] = v + b3v;
        }
    }
}

extern "C" void kernel_launch(void* const* d_in, const int* in_sizes, int n_in,
                              void* d_out, int out_size, void* d_ws, size_t ws_size,
                              hipStream_t stream) {
    const float* x  = (const float*)d_in[0];
    const float* w1 = (const float*)d_in[1];
    const float* b1 = (const float*)d_in[2];
    const float* w2 = (const float*)d_in[3];
    const float* b2 = (const float*)d_in[4];
    const float* w3 = (const float*)d_in[5];
    const float* b3 = (const float*)d_in[6];
    float* out = (float*)d_out;

    u16* w1f = (u16*)d_ws;                              // 8*8192 frags = 1 MB
    u16* w2f = w1f + (size_t)BB * 8192 * 8;             // 8*32768 frags = 4 MB

    prep_w1f<<<(BB * 4 * 32 * 64) / 256, 256, 0, stream>>>(w1, w1f);
    prep_w2f<<<(BB * 16 * 32 * 64) / 256, 256, 0, stream>>>(w2, w2f);

    // grid.x = batch (XCD round-robin), grid.y = 64-row tile
    fused_mlp<<<dim3(BB, T_TEST / 64), 256, 0, stream>>>(
        x, w1f, b1, w2f, b2, w3, b3, out);
}

// Round 4
// 144.878 us; speedup vs baseline: 1.5092x; 1.2837x over previous
//
#include <hip/hip_runtime.h>

#define T_TEST 8192
#define BB 8
#define FF 100
#define HH 512

typedef __bf16 bf16x8 __attribute__((ext_vector_type(8)));
typedef float f32x4 __attribute__((ext_vector_type(4)));
typedef unsigned short u16;
typedef unsigned int u32;

__device__ __forceinline__ u16 f2bf(float f) {
    u32 u = __float_as_uint(f);
    u += 0x7fffu + ((u >> 16) & 1);   // RNE
    return (u16)(u >> 16);
}

__device__ __forceinline__ float nan2num(float v) {
    u32 u = __float_as_uint(v);
    if ((u & 0x7f800000u) == 0x7f800000u) {
        v = (u & 0x007fffffu) ? 0.f : ((u >> 31) ? -3.3895314e38f : 3.3895314e38f);
    }
    return v;
}

// ---- weight prep: fragment-major, group-contiguous layouts -------------
// w1f frag index: ((b*4 + kk)*32 + n16)*64 + lane ; frag = 8 bf16 (16B)
// value[j] = w1[b][k=kk*32+q*8+j][n=n16*16+c]   (c=lane&15, q=lane>>4)
__global__ void prep_w1f(const float* __restrict__ w1, u16* __restrict__ w1f) {
    int tid = blockIdx.x * 256 + threadIdx.x;       // 65536 threads
    int lane = tid & 63;
    int kk = (tid >> 6) & 3;
    int n16 = (tid >> 8) & 31;
    int b = tid >> 13;
    int cc = lane & 15, qq = lane >> 4;
    int n = n16 * 16 + cc;
    u32 p[4];
#pragma unroll
    for (int jp = 0; jp < 4; ++jp) {
        int k0 = kk * 32 + qq * 8 + jp * 2;
        float v0 = (k0 < FF)     ? w1[(b * FF + k0) * HH + n]     : 0.f;
        float v1 = (k0 + 1 < FF) ? w1[(b * FF + k0 + 1) * HH + n] : 0.f;
        p[jp] = (u32)f2bf(v0) | ((u32)f2bf(v1) << 16);
    }
    uint4 o = {p[0], p[1], p[2], p[3]};
    size_t fi = ((size_t)(b * 4 + kk) * 32 + n16) * 64 + lane;
    *(uint4*)(w1f + fi * 8) = o;
}

// w2f frag index: ((b*16 + kk)*32 + n16)*64 + lane
__global__ void prep_w2f(const float* __restrict__ w2, u16* __restrict__ w2f) {
    int tid = blockIdx.x * 256 + threadIdx.x;       // 262144 threads
    int lane = tid & 63;
    int kk = (tid >> 6) & 15;
    int n16 = (tid >> 10) & 31;
    int b = tid >> 15;
    int cc = lane & 15, qq = lane >> 4;
    int n = n16 * 16 + cc;
    u32 p[4];
#pragma unroll
    for (int jp = 0; jp < 4; ++jp) {
        int k0 = kk * 32 + qq * 8 + jp * 2;
        float v0 = w2[(b * HH + k0) * HH + n];
        float v1 = w2[(b * HH + k0 + 1) * HH + n];
        p[jp] = (u32)f2bf(v0) | ((u32)f2bf(v1) << 16);
    }
    uint4 o = {p[0], p[1], p[2], p[3]};
    size_t fi = ((size_t)(b * 16 + kk) * 32 + n16) * 64 + lane;
    *(uint4*)(w2f + fi * 8) = o;
}

// swizzled LDS index helpers (granule = 8 u16 = 16B; xor low-3 granule bits by row&7)
__device__ __forceinline__ int x_idx(int row, int k) {     // [64][128]
    int g = k >> 3;
    int gp = (g & ~7) | ((g ^ row) & 7);
    return row * 128 + gp * 8 + (k & 7);
}
__device__ __forceinline__ int h1_idx(int row, int col) {  // [64][512]
    int g = col >> 3;
    int gp = (g & ~7) | ((g ^ row) & 7);
    return row * 512 + gp * 8 + (col & 7);
}

// ---- fused 3-layer MLP: 64 rows/block, 8 waves n-sliced, mi=4 row-tiles ----
__global__ __launch_bounds__(512, 4) void fused_mlp(
    const float* __restrict__ x, const u16* __restrict__ w1f,
    const float* __restrict__ b1, const u16* __restrict__ w2f,
    const float* __restrict__ b2, const float* __restrict__ w3,
    const float* __restrict__ b3, float* __restrict__ out) {
    __shared__ __align__(16) u16 h1_lds[64 * 512];   // 64 KB
    __shared__ __align__(16) u16 x_lds[64 * 128];    // 16 KB (also reused as part[])

    const int tid = threadIdx.x;
    const int b = blockIdx.x;              // batch -> XCD affinity (linear%8==b)
    const int m0 = blockIdx.y * 64;
    const int lane = tid & 63;
    const int w = tid >> 6;                // wave 0..7, owns n-slice w*64..+64
    const int c = lane & 15, q = lane >> 4;
    const int n16b = w * 4;

    const bf16x8* W1 = (const bf16x8*)w1f + (size_t)b * 8192;
    const bf16x8* W2 = (const bf16x8*)w2f + (size_t)b * 32768;

    // issue first B-fragment loads before staging (overlap with x stage)
    bf16x8 bc[4], bn[4];
#pragma unroll
    for (int ni = 0; ni < 4; ++ni)
        bc[ni] = W1[(0 * 32 + n16b + ni) * 64 + lane];

    // ---- stage x: 8 threads/row, bf16, swizzled, k 100..127 zeroed ----
    {
        int row = tid >> 3, sub = tid & 7;
        const float* xr = x + ((size_t)(m0 + row) * BB + b) * FF;
        float4 v0 = *(const float4*)(xr + sub * 4);
        float4 v1 = *(const float4*)(xr + 32 + sub * 4);
        float4 v2 = *(const float4*)(xr + 64 + sub * 4);
        auto xw = [&](int k, float4 v) {
            ushort4 h;
            h.x = f2bf(nan2num(v.x));
            h.y = f2bf(nan2num(v.y));
            h.z = f2bf(nan2num(v.z));
            h.w = f2bf(nan2num(v.w));
            *(ushort4*)(&x_lds[x_idx(row, k)]) = h;
        };
        xw(sub * 4, v0);
        xw(32 + sub * 4, v1);
        xw(64 + sub * 4, v2);
        if (sub == 0) {
            float4 v3 = *(const float4*)(xr + 96);
            xw(96, v3);                                   // k 96..99
            ushort4 z = {0, 0, 0, 0};
            *(ushort4*)(&x_lds[x_idx(row, 100)]) = z;     // k 100..103
        } else if (sub <= 3) {
            int4 z = {0, 0, 0, 0};
            *(int4*)(&x_lds[x_idx(row, 96 + sub * 8)]) = z;   // k 104..127
        }
    }
    __syncthreads();

    // ---- layer 1: acc1[mi][ni] covers rows mi*16..+16, cols w*64+ni*16..+16 ----
    f32x4 acc1[4][4] = {};
#pragma unroll
    for (int kk = 0; kk < 4; ++kk) {
        if (kk < 3) {
#pragma unroll
            for (int ni = 0; ni < 4; ++ni)
                bn[ni] = W1[((kk + 1) * 32 + n16b + ni) * 64 + lane];
        }
        bf16x8 a[4];
#pragma unroll
        for (int mi = 0; mi < 4; ++mi)
            a[mi] = *(const bf16x8*)(&x_lds[x_idx(mi * 16 + c, (kk * 4 + q) * 8)]);
#pragma unroll
        for (int mi = 0; mi < 4; ++mi)
#pragma unroll
            for (int ni = 0; ni < 4; ++ni)
                acc1[mi][ni] = __builtin_amdgcn_mfma_f32_16x16x32_bf16(a[mi], bc[ni], acc1[mi][ni], 0, 0, 0);
        if (kk < 3) {
#pragma unroll
            for (int ni = 0; ni < 4; ++ni) bc[ni] = bn[ni];
        }
    }

    // prefetch first phase-2 B frags while writing h1
#pragma unroll
    for (int ni = 0; ni < 4; ++ni)
        bc[ni] = W2[(0 * 32 + n16b + ni) * 64 + lane];

    // ---- epilogue 1: relu(acc1+b1) -> h1_lds (paired dword writes) ----
    {
        u32* h32 = (u32*)h1_lds;
        const float* b1g = b1 + b * HH;
#pragma unroll
        for (int ni = 0; ni < 4; ++ni) {
            int n = w * 64 + ni * 16 + c;
            float b1v = b1g[n];
            int ncol = n & ~1;
#pragma unroll
            for (int mi = 0; mi < 4; ++mi) {
                u32 own01 = (u32)f2bf(fmaxf(acc1[mi][ni][0] + b1v, 0.f)) |
                            ((u32)f2bf(fmaxf(acc1[mi][ni][1] + b1v, 0.f)) << 16);
                u32 own23 = (u32)f2bf(fmaxf(acc1[mi][ni][2] + b1v, 0.f)) |
                            ((u32)f2bf(fmaxf(acc1[mi][ni][3] + b1v, 0.f)) << 16);
                u32 oth01 = __shfl_xor(own01, 1, 64);
                u32 oth23 = __shfl_xor(own23, 1, 64);
                int row0 = mi * 16 + q * 4;
                if (!(c & 1)) {
                    u32 d0 = (own01 & 0xffffu) | (oth01 << 16);
                    u32 d1 = (own01 >> 16) | (oth01 & 0xffff0000u);
                    h32[h1_idx(row0, ncol) >> 1] = d0;
                    h32[h1_idx(row0 + 1, ncol) >> 1] = d1;
                } else {
                    u32 d2 = (oth23 & 0xffffu) | (own23 << 16);
                    u32 d3 = (oth23 >> 16) | (own23 & 0xffff0000u);
                    h32[h1_idx(row0 + 2, ncol) >> 1] = d2;
                    h32[h1_idx(row0 + 3, ncol) >> 1] = d3;
                }
            }
        }
    }
    __syncthreads();   // h1 visible to all waves

    // ---- layer 2: acc2[mi][ni], A from h1_lds (full k=512), B from W2f ----
    f32x4 acc2[4][4] = {};
#pragma unroll
    for (int kk = 0; kk < 16; ++kk) {
        if (kk < 15) {
#pragma unroll
            for (int ni = 0; ni < 4; ++ni)
                bn[ni] = W2[((kk + 1) * 32 + n16b + ni) * 64 + lane];
        }
        bf16x8 a[4];
#pragma unroll
        for (int mi = 0; mi < 4; ++mi)
            a[mi] = *(const bf16x8*)(&h1_lds[h1_idx(mi * 16 + c, (kk * 4 + q) * 8)]);
#pragma unroll
        for (int mi = 0; mi < 4; ++mi)
#pragma unroll
            for (int ni = 0; ni < 4; ++ni)
                acc2[mi][ni] = __builtin_amdgcn_mfma_f32_16x16x32_bf16(a[mi], bc[ni], acc2[mi][ni], 0, 0, 0);
        if (kk < 15) {
#pragma unroll
            for (int ni = 0; ni < 4; ++ni) bc[ni] = bn[ni];
        }
    }

    // ---- layer 3: fold n-slice, reduce over c, cross-wave via LDS ----
    float ps[4][4] = {};   // [mi][r]
    {
        const float* b2g = b2 + b * HH;
        const float* w3g = w3 + b * HH;
#pragma unroll
        for (int ni = 0; ni < 4; ++ni) {
            int n = w * 64 + ni * 16 + c;
            float b2v = b2g[n];
            float w3v = w3g[n];
#pragma unroll
            for (int mi = 0; mi < 4; ++mi)
#pragma unroll
                for (int r = 0; r < 4; ++r)
                    ps[mi][r] += fmaxf(acc2[mi][ni][r] + b2v, 0.f) * w3v;
        }
    }
    float* part = (float*)x_lds;   // [8][64], x dead (all reads pre-h1-barrier)
#pragma unroll
    for (int mi = 0; mi < 4; ++mi)
#pragma unroll
        for (int r = 0; r < 4; ++r) {
            float v = ps[mi][r];
            v += __shfl_xor(v, 1, 64);
            v += __shfl_xor(v, 2, 64);
            v += __shfl_xor(v, 4, 64);
            v += __shfl_xor(v, 8, 64);
            if (c == 0) part[w * 64 + mi * 16 + q * 4 + r] = v;
        }
    __syncthreads();
    if (tid < 64) {
        float s = b3[b];
#pragma unroll
        for (int ww = 0; ww < 8; ++ww) s += part[ww * 64 + tid];
        out[(size_t)(m0 + tid) * BB + b] = s;
    }
}

extern "C" void kernel_launch(void* const* d_in, const int* in_sizes, int n_in,
                              void* d_out, int out_size, void* d_ws, size_t ws_size,
                              hipStream_t stream) {
    const float* x  = (const float*)d_in[0];
    const float* w1 = (const float*)d_in[1];
    const float* b1 = (const float*)d_in[2];
    const float* w2 = (const float*)d_in[3];
    const float* b2 = (const float*)d_in[4];
    const float* w3 = (const float*)d_in[5];
    const float* b3 = (const float*)d_in[6];
    float* out = (float*)d_out;

    u16* w1f = (u16*)d_ws;                              // 8*8192 frags = 1 MB
    u16* w2f = w1f + (size_t)BB * 8192 * 8;             // 8*32768 frags = 4 MB

    prep_w1f<<<(BB * 4 * 32 * 64) / 256, 256, 0, stream>>>(w1, w1f);
    prep_w2f<<<(BB * 16 * 32 * 64) / 256, 256, 0, stream>>>(w2, w2f);

    // grid.x = batch (XCD round-robin), grid.y = 64-row tile
    fused_mlp<<<dim3(BB, T_TEST / 64), 512, 0, stream>>>(
        x, w1f, b1, w2f, b2, w3, b3, out);
}

// Round 5
// 137.328 us; speedup vs baseline: 1.5921x; 1.0550x over previous
//
#include <hip/hip_runtime.h>

#define T_TEST 8192
#define BB 8
#define FF 100
#define HH 512

typedef __bf16 bf16x8 __attribute__((ext_vector_type(8)));
typedef float f32x16 __attribute__((ext_vector_type(16)));
typedef unsigned short u16;
typedef unsigned int u32;

__device__ __forceinline__ u16 f2bf(float f) {
    u32 u = __float_as_uint(f);
    u += 0x7fffu + ((u >> 16) & 1);   // RNE
    return (u16)(u >> 16);
}

__device__ __forceinline__ float nan2num(float v) {
    u32 u = __float_as_uint(v);
    if ((u & 0x7f800000u) == 0x7f800000u) {
        v = (u & 0x007fffffu) ? 0.f : ((u >> 31) ? -3.3895314e38f : 3.3895314e38f);
    }
    return v;
}

// ---- combined weight prep: 32x32x16 fragment-major layouts -------------
// A 32x32x16 B-frag: B[k][n], n = lane&31, k = (lane>>5)*8 + j, 8 bf16/lane.
// w1f frag idx: ((b*8  + ks)*16 + n32)*64 + lane   (K=128 padded -> ks 0..7)
// w2f frag idx: ((b*32 + ks)*16 + n32)*64 + lane   (K=512        -> ks 0..31)
__global__ void prep_w(const float* __restrict__ w1, const float* __restrict__ w2,
                       u16* __restrict__ w1f, u16* __restrict__ w2f) {
    int bid = blockIdx.x;
    if (bid < 256) {                      // w1f: 65536 threads
        int t = bid * 256 + threadIdx.x;
        int lane = t & 63;
        int n32 = (t >> 6) & 15;
        int ks = (t >> 10) & 7;
        int b = t >> 13;
        int n = n32 * 32 + (lane & 31);
        int kb = ks * 16 + (lane >> 5) * 8;
        u32 p[4];
#pragma unroll
        for (int jp = 0; jp < 4; ++jp) {
            int k0 = kb + jp * 2;
            float v0 = (k0 < FF)     ? w1[(b * FF + k0) * HH + n]     : 0.f;
            float v1 = (k0 + 1 < FF) ? w1[(b * FF + k0 + 1) * HH + n] : 0.f;
            p[jp] = (u32)f2bf(v0) | ((u32)f2bf(v1) << 16);
        }
        uint4 o = {p[0], p[1], p[2], p[3]};
        *(uint4*)(w1f + (size_t)t * 8) = o;   // t == frag index by construction
    } else {                              // w2f: 262144 threads
        int t = (bid - 256) * 256 + threadIdx.x;
        int lane = t & 63;
        int n32 = (t >> 6) & 15;
        int ks = (t >> 10) & 31;
        int b = t >> 15;
        int n = n32 * 32 + (lane & 31);
        int kb = ks * 16 + (lane >> 5) * 8;
        u32 p[4];
#pragma unroll
        for (int jp = 0; jp < 4; ++jp) {
            int k0 = kb + jp * 2;
            float v0 = w2[(b * HH + k0) * HH + n];
            float v1 = w2[(b * HH + k0 + 1) * HH + n];
            p[jp] = (u32)f2bf(v0) | ((u32)f2bf(v1) << 16);
        }
        uint4 o = {p[0], p[1], p[2], p[3]};
        *(uint4*)(w2f + (size_t)t * 8) = o;
    }
}

// swizzled LDS indices: granule = 8 u16 = 16B; xor low-4 granule bits by row&15.
__device__ __forceinline__ int x_idx(int row, int k) {     // [64][128] bf16
    int g = k >> 3;
    int gp = g ^ (row & 15);               // 16 granules/row
    return row * 128 + gp * 8 + (k & 7);
}
__device__ __forceinline__ int h1_idx(int row, int col) {  // [64][512] bf16
    int g = col >> 3;
    int gp = (g & ~15) | ((g ^ row) & 15); // 64 granules/row
    return row * 512 + gp * 8 + (col & 7);
}

// ---- fused 3-layer MLP: 64 rows/block, 8 waves n-sliced (64 cols each),
// ---- 32x32x16 MFMA, 2x2 tiles/wave, depth-2 B prefetch, 3 barriers ----
__global__ __launch_bounds__(512, 4) void fused_mlp(
    const float* __restrict__ x, const u16* __restrict__ w1f,
    const float* __restrict__ b1, const u16* __restrict__ w2f,
    const float* __restrict__ b2, const float* __restrict__ w3,
    const float* __restrict__ b3, float* __restrict__ out) {
    __shared__ __align__(16) u16 h1_lds[64 * 512];   // 64 KB
    __shared__ __align__(16) u16 x_lds[64 * 128];    // 16 KB (reused as part[])

    const int tid = threadIdx.x;
    const int b = blockIdx.x;              // batch -> XCD affinity
    const int m0 = blockIdx.y * 64;
    const int lane = tid & 63;
    const int w = tid >> 6;                // wave 0..7 owns cols w*64..+64
    const int l31 = lane & 31, lh = lane >> 5;
    const int n32b = w * 2;

    const bf16x8* W1 = (const bf16x8*)w1f + (size_t)b * (8 * 16 * 64);
    const bf16x8* W2 = (const bf16x8*)w2f + (size_t)b * (32 * 16 * 64);

    // preload layer-1 ks=0,1 B-frags (latency covered by x staging)
    bf16x8 bb[2][2];
    bb[0][0] = W1[(0 * 16 + n32b + 0) * 64 + lane];
    bb[0][1] = W1[(0 * 16 + n32b + 1) * 64 + lane];
    bb[1][0] = W1[(1 * 16 + n32b + 0) * 64 + lane];
    bb[1][1] = W1[(1 * 16 + n32b + 1) * 64 + lane];

    // ---- stage x: 8 threads/row, bf16, swizzled, k 100..127 zeroed ----
    {
        int row = tid >> 3, sub = tid & 7;
        const float* xr = x + ((size_t)(m0 + row) * BB + b) * FF;
        float4 v0 = *(const float4*)(xr + sub * 4);
        float4 v1 = *(const float4*)(xr + 32 + sub * 4);
        float4 v2 = *(const float4*)(xr + 64 + sub * 4);
        auto xw = [&](int k, float4 v) {
            ushort4 h;
            h.x = f2bf(nan2num(v.x));
            h.y = f2bf(nan2num(v.y));
            h.z = f2bf(nan2num(v.z));
            h.w = f2bf(nan2num(v.w));
            *(ushort4*)(&x_lds[x_idx(row, k)]) = h;
        };
        xw(sub * 4, v0);
        xw(32 + sub * 4, v1);
        xw(64 + sub * 4, v2);
        if (sub == 0) {
            float4 v3 = *(const float4*)(xr + 96);
            xw(96, v3);                                   // k 96..99
            ushort4 z = {0, 0, 0, 0};
            *(ushort4*)(&x_lds[x_idx(row, 100)]) = z;     // k 100..103
        } else if (sub <= 3) {
            int4 z = {0, 0, 0, 0};
            *(int4*)(&x_lds[x_idx(row, 96 + sub * 8)]) = z;   // k 104..127
        }
    }
    __syncthreads();

    // ---- layer 1: acc1[mi][ni], rows mi*32..+32, cols (n32b+ni)*32..+32 ----
    f32x16 acc1[2][2] = {};
#pragma unroll
    for (int ks = 0; ks < 8; ++ks) {
        bf16x8 a0 = *(const bf16x8*)(&x_lds[x_idx(l31,      (2 * ks + lh) * 8)]);
        bf16x8 a1 = *(const bf16x8*)(&x_lds[x_idx(32 + l31, (2 * ks + lh) * 8)]);
        acc1[0][0] = __builtin_amdgcn_mfma_f32_32x32x16_bf16(a0, bb[ks & 1][0], acc1[0][0], 0, 0, 0);
        acc1[0][1] = __builtin_amdgcn_mfma_f32_32x32x16_bf16(a0, bb[ks & 1][1], acc1[0][1], 0, 0, 0);
        acc1[1][0] = __builtin_amdgcn_mfma_f32_32x32x16_bf16(a1, bb[ks & 1][0], acc1[1][0], 0, 0, 0);
        acc1[1][1] = __builtin_amdgcn_mfma_f32_32x32x16_bf16(a1, bb[ks & 1][1], acc1[1][1], 0, 0, 0);
        if (ks < 6) {
            bb[ks & 1][0] = W1[((ks + 2) * 16 + n32b + 0) * 64 + lane];
            bb[ks & 1][1] = W1[((ks + 2) * 16 + n32b + 1) * 64 + lane];
        }
    }

    // preload layer-2 ks=0,1 (latency covered by epilogue-1 + barrier)
    bb[0][0] = W2[(0 * 16 + n32b + 0) * 64 + lane];
    bb[0][1] = W2[(0 * 16 + n32b + 1) * 64 + lane];
    bb[1][0] = W2[(1 * 16 + n32b + 0) * 64 + lane];
    bb[1][1] = W2[(1 * 16 + n32b + 1) * 64 + lane];

    // ---- epilogue 1: relu(acc1+b1) -> h1_lds (paired dword writes) ----
    // C/D layout 32x32: col = lane&31, row = (r&3) + 8*(r>>2) + 4*(lane>>5)
    {
        u32* h32 = (u32*)h1_lds;
        const float* b1g = b1 + b * HH;
#pragma unroll
        for (int ni = 0; ni < 2; ++ni) {
            int n = (n32b + ni) * 32 + l31;
            float b1v = b1g[n];
            int ncol = n & ~1;
#pragma unroll
            for (int mi = 0; mi < 2; ++mi)
#pragma unroll
                for (int qd = 0; qd < 4; ++qd) {
                    u32 own01 = (u32)f2bf(fmaxf(acc1[mi][ni][qd * 4 + 0] + b1v, 0.f)) |
                                ((u32)f2bf(fmaxf(acc1[mi][ni][qd * 4 + 1] + b1v, 0.f)) << 16);
                    u32 own23 = (u32)f2bf(fmaxf(acc1[mi][ni][qd * 4 + 2] + b1v, 0.f)) |
                                ((u32)f2bf(fmaxf(acc1[mi][ni][qd * 4 + 3] + b1v, 0.f)) << 16);
                    u32 oth01 = __shfl_xor(own01, 1, 64);
                    u32 oth23 = __shfl_xor(own23, 1, 64);
                    int row0 = mi * 32 + qd * 8 + lh * 4;
                    if (!(lane & 1)) {
                        u32 d0 = (own01 & 0xffffu) | (oth01 << 16);
                        u32 d1 = (own01 >> 16) | (oth01 & 0xffff0000u);
                        h32[h1_idx(row0, ncol) >> 1] = d0;
                        h32[h1_idx(row0 + 1, ncol) >> 1] = d1;
                    } else {
                        u32 d2 = (oth23 & 0xffffu) | (own23 << 16);
                        u32 d3 = (oth23 >> 16) | (own23 & 0xffff0000u);
                        h32[h1_idx(row0 + 2, ncol) >> 1] = d2;
                        h32[h1_idx(row0 + 3, ncol) >> 1] = d3;
                    }
                }
        }
    }
    __syncthreads();   // h1 visible to all waves

    // ---- layer 2: full k=512 from h1_lds, depth-2 B prefetch ----
    f32x16 acc2[2][2] = {};
#pragma unroll
    for (int ks = 0; ks < 32; ++ks) {
        bf16x8 a0 = *(const bf16x8*)(&h1_lds[h1_idx(l31,      (2 * ks + lh) * 8)]);
        bf16x8 a1 = *(const bf16x8*)(&h1_lds[h1_idx(32 + l31, (2 * ks + lh) * 8)]);
        acc2[0][0] = __builtin_amdgcn_mfma_f32_32x32x16_bf16(a0, bb[ks & 1][0], acc2[0][0], 0, 0, 0);
        acc2[0][1] = __builtin_amdgcn_mfma_f32_32x32x16_bf16(a0, bb[ks & 1][1], acc2[0][1], 0, 0, 0);
        acc2[1][0] = __builtin_amdgcn_mfma_f32_32x32x16_bf16(a1, bb[ks & 1][0], acc2[1][0], 0, 0, 0);
        acc2[1][1] = __builtin_amdgcn_mfma_f32_32x32x16_bf16(a1, bb[ks & 1][1], acc2[1][1], 0, 0, 0);
        if (ks < 30) {
            bb[ks & 1][0] = W2[((ks + 2) * 16 + n32b + 0) * 64 + lane];
            bb[ks & 1][1] = W2[((ks + 2) * 16 + n32b + 1) * 64 + lane];
        }
    }

    // ---- layer 3: fold n-slice in-register, reduce over 32 cols ----
    const float* b2g = b2 + b * HH;
    const float* w3g = w3 + b * HH;
    float b2v0 = b2g[(n32b + 0) * 32 + l31], w3v0 = w3g[(n32b + 0) * 32 + l31];
    float b2v1 = b2g[(n32b + 1) * 32 + l31], w3v1 = w3g[(n32b + 1) * 32 + l31];
    float* part = (float*)x_lds;   // [8][64]; x dead (all reads pre-h1-barrier)
#pragma unroll
    for (int mi = 0; mi < 2; ++mi)
#pragma unroll
        for (int r = 0; r < 16; ++r) {
            float v = fmaxf(acc2[mi][0][r] + b2v0, 0.f) * w3v0 +
                      fmaxf(acc2[mi][1][r] + b2v1, 0.f) * w3v1;
            v += __shfl_xor(v, 1, 64);
            v += __shfl_xor(v, 2, 64);
            v += __shfl_xor(v, 4, 64);
            v += __shfl_xor(v, 8, 64);
            v += __shfl_xor(v, 16, 64);
            if (l31 == 0)
                part[w * 64 + mi * 32 + (r & 3) + 8 * (r >> 2) + 4 * lh] = v;
        }
    __syncthreads();
    if (tid < 64) {
        float s = b3[b];
#pragma unroll
        for (int ww = 0; ww < 8; ++ww) s += part[ww * 64 + tid];
        out[(size_t)(m0 + tid) * BB + b] = s;
    }
}

extern "C" void kernel_launch(void* const* d_in, const int* in_sizes, int n_in,
                              void* d_out, int out_size, void* d_ws, size_t ws_size,
                              hipStream_t stream) {
    const float* x  = (const float*)d_in[0];
    const float* w1 = (const float*)d_in[1];
    const float* b1 = (const float*)d_in[2];
    const float* w2 = (const float*)d_in[3];
    const float* b2 = (const float*)d_in[4];
    const float* w3 = (const float*)d_in[5];
    const float* b3 = (const float*)d_in[6];
    float* out = (float*)d_out;

    u16* w1f = (u16*)d_ws;                              // 8*8192 frags  = 1 MB
    u16* w2f = w1f + (size_t)BB * 8192 * 8;             // 8*32768 frags = 4 MB

    prep_w<<<1280, 256, 0, stream>>>(w1, w2, w1f, w2f);

    // grid.x = batch (XCD round-robin), grid.y = 64-row tile
    fused_mlp<<<dim3(BB, T_TEST / 64), 512, 0, stream>>>(
        x, w1f, b1, w2f, b2, w3, b3, out);
}